// Round 1
// baseline (1566.253 us; speedup 1.0000x reference)
//
#include <hip/hip_runtime.h>
#include <math.h>

#define V 30000
#define E 200
#define T 100
#define N 2048
#define NITER 100
#define EPS_OT 1e-16f
#define EPS_LOG 1e-12f

// workspace float offsets
#define OFF_KTW   0            // T*V = 3,000,000   K_TW[t][j]
#define OFF_KDT   3000000      // N*T = 204,800     K_DT[n][t]
#define OFF_BTW   3204800      // V                 softmax(word_weights)
#define OFF_BDT   3234800      // 128               softmax(topic_weights)
#define OFF_WW    3234928      // V                 ||word||^2
#define OFF_DD    3264928      // N                 ||doc||^2
#define OFF_TT    3266976      // 128               ||topic||^2
#define OFF_ACCTW 3267104      // NITER*T           per-iter K v accumulators (TW)
#define OFF_ACCDT 3277104      // NITER*T           per-iter K^T u accumulators (DT)
#define OFF_VTW   3287104      // V                 current v (TW)
#define OFF_UDT   3317104      // N                 final u (DT)
#define OFF_UTW   3319152      // 128               final u (TW)
#define OFF_VDT   3319280      // 128               final v (DT)
#define OFF_DBL   3319408      // 6 floats = 3 doubles: [0]=dsr_sum [1]=loss_dt [2]=loss_tw

// ---------- squared row norms of word/doc/topic embeddings ----------
__global__ void k_norms(const float* __restrict__ we, const float* __restrict__ de,
                        const float* __restrict__ te, float* ws) {
    int r = blockIdx.x * 256 + threadIdx.x;
    const float* src; float* dst; int row;
    if (r < V)                { src = we; dst = ws + OFF_WW; row = r; }
    else if (r < V + N)       { src = de; dst = ws + OFF_DD; row = r - V; }
    else if (r < V + N + T)   { src = te; dst = ws + OFF_TT; row = r - V - N; }
    else return;
    const float4* p = (const float4*)(src + (size_t)row * E);
    float s = 0.f;
    #pragma unroll 10
    for (int i = 0; i < E / 4; i++) { float4 v = p[i]; s += v.x*v.x + v.y*v.y + v.z*v.z + v.w*v.w; }
    dst[row] = s;
}

// ---------- zero accumulators + softmax(word_weights) + softmax(topic_weights) ----------
__global__ void k_setup(const float* __restrict__ wwgt, const float* __restrict__ twgt, float* ws) {
    __shared__ float red[256];
    int tid = threadIdx.x;
    int gid = blockIdx.x * 256 + tid;
    if (gid < 2 * NITER * T) ws[OFF_ACCTW + gid] = 0.f;
    if (gid < 6) ws[OFF_DBL + gid] = 0.f;

    // block-redundant softmax over word_weights (deterministic & identical per block)
    float m = -INFINITY;
    for (int j = tid; j < V; j += 256) m = fmaxf(m, wwgt[j]);
    red[tid] = m; __syncthreads();
    for (int s = 128; s > 0; s >>= 1) { if (tid < s) red[tid] = fmaxf(red[tid], red[tid + s]); __syncthreads(); }
    m = red[0]; __syncthreads();
    float sum = 0.f;
    for (int j = tid; j < V; j += 256) sum += expf(wwgt[j] - m);
    red[tid] = sum; __syncthreads();
    for (int s = 128; s > 0; s >>= 1) { if (tid < s) red[tid] += red[tid + s]; __syncthreads(); }
    sum = red[0]; __syncthreads();
    if (gid < V) ws[OFF_BTW + gid] = expf(wwgt[gid] - m) / sum;

    if (blockIdx.x == 0) {
        float w2 = (tid < T) ? twgt[tid] : -INFINITY;
        red[tid] = w2; __syncthreads();
        for (int s = 128; s > 0; s >>= 1) { if (tid < s) red[tid] = fmaxf(red[tid], red[tid + s]); __syncthreads(); }
        float m2 = red[0]; __syncthreads();
        float e2 = (tid < T) ? expf(w2 - m2) : 0.f;
        red[tid] = e2; __syncthreads();
        for (int s = 128; s > 0; s >>= 1) { if (tid < s) red[tid] += red[tid + s]; __syncthreads(); }
        float s2 = red[0];
        if (tid < T) ws[OFF_BDT + tid] = e2 / s2;
    }
}

// ---------- K_TW[t][j] = exp(-2 * (||t||^2 + ||w_j||^2 - 2 t.w)) ----------
__global__ void k_ktw(const float* __restrict__ we, const float* __restrict__ te, float* ws) {
    __shared__ float wt[8][256];
    __shared__ float tp[8][25];
    __shared__ float tts[25];
    int tid = threadIdx.x;
    int j0 = blockIdx.x * 256;
    int t0 = blockIdx.y * 25;
    int j = j0 + tid;
    int jl = (j < V) ? j : V - 1;
    float acc[25];
    #pragma unroll
    for (int i = 0; i < 25; i++) acc[i] = 0.f;
    if (tid < 25) tts[tid] = ws[OFF_TT + t0 + tid];
    for (int kk = 0; kk < E; kk += 8) {
        #pragma unroll
        for (int k = 0; k < 8; k++) wt[k][tid] = we[(size_t)jl * E + kk + k];
        if (tid < 200) { int i = tid >> 3; int k = tid & 7; tp[k][i] = te[(size_t)(t0 + i) * E + kk + k]; }
        __syncthreads();
        #pragma unroll
        for (int k = 0; k < 8; k++) {
            float w = wt[k][tid];
            #pragma unroll
            for (int i = 0; i < 25; i++) acc[i] += tp[k][i] * w;
        }
        __syncthreads();
    }
    if (j < V) {
        float wwj = ws[OFF_WW + j];
        #pragma unroll
        for (int i = 0; i < 25; i++) {
            float M = tts[i] + wwj - 2.f * acc[i];
            ws[OFF_KTW + (size_t)(t0 + i) * V + j] = expf(-2.f * M);
        }
    }
}

// ---------- K_DT[n][t] = exp(-3 * sqdist(doc_n, topic_t)) ----------
__global__ void k_kdt(const float* __restrict__ de, const float* __restrict__ te, float* ws) {
    int gid = blockIdx.x * 256 + threadIdx.x;
    if (gid >= N * T) return;
    int n = gid / T; int t = gid - n * T;
    const float4* dp  = (const float4*)(de + (size_t)n * E);
    const float4* tpp = (const float4*)(te + (size_t)t * E);
    float s = 0.f;
    #pragma unroll 10
    for (int i = 0; i < E / 4; i++) { float4 a = dp[i], b = tpp[i]; s += a.x*b.x + a.y*b.y + a.z*b.z + a.w*b.w; }
    float M = ws[OFF_DD + n] + ws[OFF_TT + t] - 2.f * s;
    ws[OFF_KDT + gid] = expf(-3.f * M);
}

// ---------- one sinkhorn iteration (TW on blocks 0..117, DT on blocks 128..255) ----------
__global__ void k_iter(float* ws, int k) {
    __shared__ float sh[256];
    __shared__ float sh2[256];
    int tid = threadIdx.x;
    int b = blockIdx.x;
    if (b < 118) {
        // u^{(k)}: redundant per block from acc of previous iteration
        if (tid < T) sh[tid] = (k == 0) ? 0.01f : 0.01f / (ws[OFF_ACCTW + (k - 1) * T + tid] + EPS_OT);
        __syncthreads();
        int j = b * 256 + tid;
        float v = 0.f;
        if (j < V) {
            const float* Kc = ws + OFF_KTW + j;
            float s0 = 0.f, s1 = 0.f, s2 = 0.f, s3 = 0.f;
            for (int t = 0; t < T; t += 4) {
                s0 += Kc[(size_t)(t + 0) * V] * sh[t + 0];
                s1 += Kc[(size_t)(t + 1) * V] * sh[t + 1];
                s2 += Kc[(size_t)(t + 2) * V] * sh[t + 2];
                s3 += Kc[(size_t)(t + 3) * V] * sh[t + 3];
            }
            float s = (s0 + s1) + (s2 + s3);
            v = ws[OFF_BTW + j] / (s + EPS_OT);
            ws[OFF_VTW + j] = v;
        }
        sh2[tid] = v;
        __syncthreads();
        if (tid < T) {
            int nc4 = (b == 117) ? (V - 117 * 256) / 4 : 64;
            const float4* Kr = (const float4*)(ws + OFF_KTW + (size_t)tid * V + b * 256);
            float s = 0.f;
            for (int c = 0; c < nc4; c++) {
                float4 kq = Kr[c];
                s += kq.x * sh2[4*c] + kq.y * sh2[4*c+1] + kq.z * sh2[4*c+2] + kq.w * sh2[4*c+3];
            }
            atomicAdd(ws + OFF_ACCTW + k * T + tid, s);
        }
    } else if (b >= 128) {
        int d0 = (b - 128) * 16;
        if (k > 0 && tid < T) sh[tid] = ws[OFF_BDT + tid] / (ws[OFF_ACCDT + (k - 1) * T + tid] + EPS_OT);
        __syncthreads();
        if (tid < 16) {
            float u;
            if (k == 0) u = 1.f / 2048.f;
            else {
                const float* Kr = ws + OFF_KDT + (size_t)(d0 + tid) * T;
                float s = 0.f;
                for (int t = 0; t < T; t++) s += Kr[t] * sh[t];
                u = (1.f / 2048.f) / (s + EPS_OT);
            }
            sh2[tid] = u;
        }
        __syncthreads();
        if (tid < T) {
            float s = 0.f;
            #pragma unroll
            for (int i = 0; i < 16; i++) s += ws[OFF_KDT + (size_t)(d0 + i) * T + tid] * sh2[i];
            atomicAdd(ws + OFF_ACCDT + k * T + tid, s);
        }
    }
}

// ---------- final TW: u^{(100)}, loss_TW = sum u K v M ----------
__global__ void k_final_tw(float* ws) {
    __shared__ float us[T];
    __shared__ float red[256];
    int tid = threadIdx.x;
    if (tid < T) {
        float u = 0.01f / (ws[OFF_ACCTW + (NITER - 1) * T + tid] + EPS_OT);
        us[tid] = u;
        if (blockIdx.x == 0) ws[OFF_UTW + tid] = u;
    }
    __syncthreads();
    int j = blockIdx.x * 256 + tid;
    float part = 0.f;
    if (j < V) {
        float v = ws[OFF_VTW + j];
        for (int t = 0; t < T; t++) {
            float kv = ws[OFF_KTW + (size_t)t * V + j];
            if (kv > 0.f) part += us[t] * kv * v * (-0.5f * logf(kv));
        }
    }
    red[tid] = part; __syncthreads();
    for (int s = 128; s > 0; s >>= 1) { if (tid < s) red[tid] += red[tid + s]; __syncthreads(); }
    if (tid == 0) atomicAdd((double*)(ws + OFF_DBL) + 2, (double)red[0]);
}

// ---------- final DT: v^{(100)}, u^{(100)}, loss_DT ----------
__global__ void k_final_dt(float* ws) {
    __shared__ float vs[T];
    __shared__ float red[256];
    int tid = threadIdx.x;
    if (tid < T) {
        float v = ws[OFF_BDT + tid] / (ws[OFF_ACCDT + (NITER - 1) * T + tid] + EPS_OT);
        vs[tid] = v;
        if (blockIdx.x == 0) ws[OFF_VDT + tid] = v;
    }
    __syncthreads();
    int d = blockIdx.x * 256 + tid;
    const float* Kr = ws + OFF_KDT + (size_t)d * T;
    float s = 0.f;
    for (int t = 0; t < T; t++) s += Kr[t] * vs[t];
    float u = (1.f / 2048.f) / (s + EPS_OT);
    ws[OFF_UDT + d] = u;
    float part = 0.f;
    for (int t = 0; t < T; t++) {
        float kv = Kr[t];
        if (kv > 0.f) part += u * kv * vs[t] * (-(1.f / 3.f) * logf(kv));
    }
    red[tid] = part; __syncthreads();
    for (int s2 = 128; s2 > 0; s2 >>= 1) { if (tid < s2) red[tid] += red[tid + s2]; __syncthreads(); }
    if (tid == 0) atomicAdd((double*)(ws + OFF_DBL) + 1, (double)red[0]);
}

// ---------- DSR: recon = theta @ beta (recomputed on the fly), with theta==0 fast path ----------
__global__ void k_dsr(const float* __restrict__ bow, float* ws) {
    __shared__ float th[32 * T];
    __shared__ float u2[T];
    __shared__ float vd[T];
    __shared__ float red[256];
    __shared__ int flag;
    int tid = threadIdx.x;
    int j0 = blockIdx.x * 256;
    int d0 = blockIdx.y * 32;
    if (tid < T) { vd[tid] = ws[OFF_VDT + tid]; u2[tid] = ws[OFF_UTW + tid]; }
    if (tid == 0) flag = 0;
    __syncthreads();
    bool nz = false;
    for (int idx = tid; idx < 32 * T; idx += 256) {
        int dl = idx / T; int t = idx - dl * T;
        float thv = 2048.f * ws[OFF_UDT + d0 + dl] * ws[OFF_KDT + (size_t)(d0 + dl) * T + t] * vd[t];
        th[idx] = thv;
        nz |= (thv != 0.f);
    }
    if (nz) flag = 1;
    __syncthreads();
    int j = j0 + tid;
    float part = 0.f;
    if (flag) {
        float acc[32];
        #pragma unroll
        for (int d = 0; d < 32; d++) acc[d] = 0.f;
        if (j < V) {
            float vj = ws[OFF_VTW + j];
            for (int t = 0; t < T; t++) {
                float kv = ws[OFF_KTW + (size_t)t * V + j];
                float beta = 100.f * u2[t] * kv * vj;
                #pragma unroll
                for (int d = 0; d < 32; d++) acc[d] += th[d * T + t] * beta;
            }
            for (int d = 0; d < 32; d++)
                part += bow[(size_t)(d0 + d) * V + j] * logf(acc[d] + EPS_LOG);
        }
    } else {
        if (j < V) {
            float sb = 0.f;
            #pragma unroll 8
            for (int d = 0; d < 32; d++) sb += bow[(size_t)(d0 + d) * V + j];
            part = sb * logf(EPS_LOG);
        }
    }
    red[tid] = part; __syncthreads();
    for (int s = 128; s > 0; s >>= 1) { if (tid < s) red[tid] += red[tid + s]; __syncthreads(); }
    if (tid == 0) atomicAdd((double*)(ws + OFF_DBL) + 0, (double)red[0]);
}

// ---------- combine ----------
__global__ void k_finish(float* ws, float* out) {
    if (threadIdx.x == 0 && blockIdx.x == 0) {
        double* dbl = (double*)(ws + OFF_DBL);
        double ldsr = -dbl[0] / (double)N;
        double letp = dbl[1] + dbl[2];
        out[0] = (float)(ldsr + letp);
        out[1] = (float)ldsr;
        out[2] = (float)letp;
    }
}

extern "C" void kernel_launch(void* const* d_in, const int* in_sizes, int n_in,
                              void* d_out, int out_size, void* d_ws, size_t ws_size,
                              hipStream_t stream) {
    const float* bow  = (const float*)d_in[0];
    const float* de   = (const float*)d_in[1];
    const float* we   = (const float*)d_in[2];
    const float* te   = (const float*)d_in[3];
    const float* wwgt = (const float*)d_in[4];
    const float* twgt = (const float*)d_in[5];
    float* out = (float*)d_out;
    float* ws  = (float*)d_ws;

    k_norms<<<126, 256, 0, stream>>>(we, de, te, ws);
    k_setup<<<118, 256, 0, stream>>>(wwgt, twgt, ws);
    k_ktw<<<dim3(118, 4), 256, 0, stream>>>(we, te, ws);
    k_kdt<<<800, 256, 0, stream>>>(de, te, ws);
    for (int k = 0; k < NITER; k++)
        k_iter<<<256, 256, 0, stream>>>(ws, k);
    k_final_tw<<<118, 256, 0, stream>>>(ws);
    k_final_dt<<<8, 256, 0, stream>>>(ws);
    k_dsr<<<dim3(118, 64), 256, 0, stream>>>(bow, ws);
    k_finish<<<1, 64, 0, stream>>>(ws, out);
}